// Round 13
// baseline (633.140 us; speedup 1.0000x reference)
//
#include <hip/hip_runtime.h>
#include <hip/hip_bf16.h>
#include <float.h>

#define N_NODES 50000
#define N_EDGES 600000
#define E_TOT   (N_EDGES + N_NODES)   /* 650000 incl. self loops */
#define NUM_GRAPHS 256
#define IN_CH 6
#define HID 128
#define NEG_SLOPE 0.2f
#define SCAN_B 512

// GEMM tile config
#define BM 64
#define BK 32

// ---------------- bf16 helpers (h table stored as raw bf16 bits) -----------
__device__ __forceinline__ unsigned short f2bf(float f) {
    unsigned int u = __float_as_uint(f);
    u += 0x7FFFu + ((u >> 16) & 1u);          // RNE
    return (unsigned short)(u >> 16);
}
__device__ __forceinline__ float bf_lo(unsigned int v) { return __uint_as_float(v << 16); }
__device__ __forceinline__ float bf_hi(unsigned int v) { return __uint_as_float(v & 0xFFFF0000u); }

// ---------------- int64-vs-int32 runtime detection -------------------------
__device__ __forceinline__ int detect_is64(const int* ei32) {
    int any = 0;
#pragma unroll
    for (int i = 1; i < 128; i += 2) any |= ei32[i];
    return any == 0;
}

__global__ void k_convert(const void* edge_index, const void* batch,
                          int* src32, int* dst32, int* batch32) {
    const int* ei32 = (const int*)edge_index;
    const int is64 = detect_is64(ei32);
    int i = blockIdx.x * blockDim.x + threadIdx.x;
    if (i < N_EDGES) {
        if (is64) {
            const long long* e = (const long long*)edge_index;
            src32[i] = (int)e[i];
            dst32[i] = (int)e[N_EDGES + i];
        } else {
            src32[i] = ei32[i];
            dst32[i] = ei32[N_EDGES + i];
        }
    }
    if (i < N_NODES) {
        batch32[i] = is64 ? (int)((const long long*)batch)[i]
                          : ((const int*)batch)[i];
    }
}

// ---------------- CSR build (counting sort by dst) -------------------------
__global__ void k_hist(const int* dst32, int* deg) {
    int e = blockIdx.x * blockDim.x + threadIdx.x;
    if (e >= E_TOT) return;
    int d = (e < N_EDGES) ? dst32[e] : (e - N_EDGES);
    atomicAdd(&deg[d], 1);
}

__global__ void k_scan1(int* deg, int* bsum) {
    __shared__ int tmp[SCAN_B];
    int i = blockIdx.x * SCAN_B + threadIdx.x;
    int v = (i < N_NODES) ? deg[i] : 0;
    tmp[threadIdx.x] = v;
    __syncthreads();
    for (int off = 1; off < SCAN_B; off <<= 1) {
        int t = (threadIdx.x >= off) ? tmp[threadIdx.x - off] : 0;
        __syncthreads();
        tmp[threadIdx.x] += t;
        __syncthreads();
    }
    if (i < N_NODES) deg[i] = tmp[threadIdx.x];
    if (threadIdx.x == SCAN_B - 1) bsum[blockIdx.x] = tmp[threadIdx.x];
}

__global__ void k_scan2(int* bsum, int nb) {
    if (blockIdx.x == 0 && threadIdx.x == 0) {
        int run = 0;
        for (int b = 0; b < nb; ++b) { int t = bsum[b]; bsum[b] = run; run += t; }
    }
}

__global__ void k_scan3(const int* incl, const int* bsum, int* offsets) {
    int i = blockIdx.x * SCAN_B + threadIdx.x;
    if (i < N_NODES) offsets[i + 1] = incl[i] + bsum[blockIdx.x];
    if (i == 0) offsets[0] = 0;
}

__global__ void k_build(const int* src32, const int* dst32, const int* offsets,
                        int* cursor, int* csr_src) {
    int e = blockIdx.x * blockDim.x + threadIdx.x;
    if (e >= E_TOT) return;
    int s, d;
    if (e < N_EDGES) { s = src32[e]; d = dst32[e]; }
    else             { s = d = e - N_EDGES; }
    int pos = offsets[d] + atomicAdd(&cursor[d], 1);
    csr_src[pos] = s;
}

// ---------------- layer-1 GEMM (K=6, trivial) ------------------------------
__global__ void k_gemm1(const float* __restrict__ x, const float* __restrict__ W,
                        const float* __restrict__ asrc, const float* __restrict__ adst,
                        unsigned short* __restrict__ h, float* al_src, float* al_dst) {
    int wave = (blockIdx.x * blockDim.x + threadIdx.x) >> 6;
    int lane = threadIdx.x & 63;
    if (wave >= N_NODES) return;
    const int n = wave;
    float h0 = 0.f, h1 = 0.f;
#pragma unroll
    for (int k = 0; k < IN_CH; ++k) {
        float xk = x[n * IN_CH + k];
        float2 w = *(const float2*)&W[k * HID + 2 * lane];
        h0 += xk * w.x; h1 += xk * w.y;
    }
    unsigned int hp = (unsigned int)f2bf(h0) | ((unsigned int)f2bf(h1) << 16);
    ((unsigned int*)h)[(size_t)n * 64 + lane] = hp;
    float2 as = *(const float2*)&asrc[2 * lane];
    float2 ad = *(const float2*)&adst[2 * lane];
    float ps = h0 * as.x + h1 * as.y;
    float pd = h0 * ad.x + h1 * ad.y;
#pragma unroll
    for (int off = 32; off; off >>= 1) {
        ps += __shfl_xor(ps, off);
        pd += __shfl_xor(pd, off);
    }
    if (lane == 0) { al_src[n] = ps; al_dst[n] = pd; }
}

// ---------------- layers 2/3 GEMM: LDS-tiled [N,128]x[128,128] -------------
__global__ __launch_bounds__(256) void k_gemm_tiled(
    const float* __restrict__ X, const float* __restrict__ W,
    const float* __restrict__ asrc, const float* __restrict__ adst,
    unsigned short* __restrict__ h, float* __restrict__ al_src, float* __restrict__ al_dst)
{
    __shared__ float As[BK][BM + 4];
    __shared__ float Bs[BK][HID];

    const int tid = threadIdx.x;
    const int node_base = blockIdx.x * BM;
    const int tn = tid & 31;
    const int tm = tid >> 5;

    float acc[8][4];
#pragma unroll
    for (int i = 0; i < 8; ++i)
#pragma unroll
        for (int j = 0; j < 4; ++j) acc[i][j] = 0.f;

    const int sa_node  = tid & 63;
    const int sa_kpart = tid >> 6;
    int gnode = node_base + sa_node;
    if (gnode >= N_NODES) gnode = N_NODES - 1;

    const int sb_k = tid >> 3;
    const int sb_c = (tid & 7) * 16;

    for (int k0 = 0; k0 < HID; k0 += BK) {
        const float4 xa = *(const float4*)&X[(size_t)gnode * HID + k0 + sa_kpart * 8];
        const float4 xb = *(const float4*)&X[(size_t)gnode * HID + k0 + sa_kpart * 8 + 4];
        {
            const int kb = sa_kpart * 8;
            As[kb + 0][sa_node] = xa.x; As[kb + 1][sa_node] = xa.y;
            As[kb + 2][sa_node] = xa.z; As[kb + 3][sa_node] = xa.w;
            As[kb + 4][sa_node] = xb.x; As[kb + 5][sa_node] = xb.y;
            As[kb + 6][sa_node] = xb.z; As[kb + 7][sa_node] = xb.w;
        }
        {
            const float* wsrc = &W[(size_t)(k0 + sb_k) * HID + sb_c];
            float4 w0 = *(const float4*)(wsrc + 0);
            float4 w1 = *(const float4*)(wsrc + 4);
            float4 w2 = *(const float4*)(wsrc + 8);
            float4 w3 = *(const float4*)(wsrc + 12);
            *(float4*)&Bs[sb_k][sb_c + 0]  = w0;
            *(float4*)&Bs[sb_k][sb_c + 4]  = w1;
            *(float4*)&Bs[sb_k][sb_c + 8]  = w2;
            *(float4*)&Bs[sb_k][sb_c + 12] = w3;
        }
        __syncthreads();

#pragma unroll
        for (int kk = 0; kk < BK; ++kk) {
            const float4 b  = *(const float4*)&Bs[kk][tn * 4];
            const float4 a0 = *(const float4*)&As[kk][tm * 8];
            const float4 a1 = *(const float4*)&As[kk][tm * 8 + 4];
            acc[0][0] += a0.x * b.x; acc[0][1] += a0.x * b.y; acc[0][2] += a0.x * b.z; acc[0][3] += a0.x * b.w;
            acc[1][0] += a0.y * b.x; acc[1][1] += a0.y * b.y; acc[1][2] += a0.y * b.z; acc[1][3] += a0.y * b.w;
            acc[2][0] += a0.z * b.x; acc[2][1] += a0.z * b.y; acc[2][2] += a0.z * b.z; acc[2][3] += a0.z * b.w;
            acc[3][0] += a0.w * b.x; acc[3][1] += a0.w * b.y; acc[3][2] += a0.w * b.z; acc[3][3] += a0.w * b.w;
            acc[4][0] += a1.x * b.x; acc[4][1] += a1.x * b.y; acc[4][2] += a1.x * b.z; acc[4][3] += a1.x * b.w;
            acc[5][0] += a1.y * b.x; acc[5][1] += a1.y * b.y; acc[5][2] += a1.y * b.z; acc[5][3] += a1.y * b.w;
            acc[6][0] += a1.z * b.x; acc[6][1] += a1.z * b.y; acc[6][2] += a1.z * b.z; acc[6][3] += a1.z * b.w;
            acc[7][0] += a1.w * b.x; acc[7][1] += a1.w * b.y; acc[7][2] += a1.w * b.z; acc[7][3] += a1.w * b.w;
        }
        __syncthreads();
    }

    const float4 as4 = *(const float4*)&asrc[tn * 4];
    const float4 ad4 = *(const float4*)&adst[tn * 4];
#pragma unroll
    for (int i = 0; i < 8; ++i) {
        const int node = node_base + tm * 8 + i;
        float ps = acc[i][0] * as4.x + acc[i][1] * as4.y + acc[i][2] * as4.z + acc[i][3] * as4.w;
        float pd = acc[i][0] * ad4.x + acc[i][1] * ad4.y + acc[i][2] * ad4.z + acc[i][3] * ad4.w;
#pragma unroll
        for (int off = 16; off; off >>= 1) {
            ps += __shfl_xor(ps, off);
            pd += __shfl_xor(pd, off);
        }
        if (node < N_NODES) {
            unsigned int u0 = (unsigned int)f2bf(acc[i][0]) | ((unsigned int)f2bf(acc[i][1]) << 16);
            unsigned int u1 = (unsigned int)f2bf(acc[i][2]) | ((unsigned int)f2bf(acc[i][3]) << 16);
            *(uint2*)(h + (size_t)node * HID + tn * 4) = make_uint2(u0, u1);
            if (tn == 0) { al_src[node] = ps; al_dst[node] = pd; }
        }
    }
}

// ---------------- GAT aggregation (gather, register-cached softmax) --------
template <int RELU>
__global__ void k_gat_aggr(const int* __restrict__ offsets, const int* __restrict__ csr_src,
                           const float* __restrict__ al_src, const float* __restrict__ al_dst,
                           const unsigned short* __restrict__ hb, const float* __restrict__ bias,
                           float* __restrict__ out) {
    int wave = (blockIdx.x * blockDim.x + threadIdx.x) >> 6;
    int lane = threadIdx.x & 63;
    if (wave >= N_NODES) return;
    const int n = wave;
    const int start = offsets[n], end = offsets[n + 1];
    const int deg = end - start;
    const float alD = al_dst[n];

    float a0 = 0.f, a1 = 0.f;
    float inv;

    if (deg <= 64) {
        // one strided gather: cache src index + exp weight per lane
        const int idx = start + (lane < deg ? lane : 0);
        const int s_reg = csr_src[idx];
        float e = al_src[s_reg] + alD;
        e = (e > 0.f) ? e : NEG_SLOPE * e;
        float ev = (lane < deg) ? e : -FLT_MAX;
#pragma unroll
        for (int off = 32; off; off >>= 1) ev = fmaxf(ev, __shfl_xor(ev, off));
        const float ex_reg = (lane < deg) ? __expf(e - ev) : 0.f;
        float den = ex_reg;
#pragma unroll
        for (int off = 32; off; off >>= 1) den += __shfl_xor(den, off);
        inv = 1.f / (den + 1e-16f);

        // weighted row gather, 1-deep pipeline; s/ex broadcast from registers
        int s_cur = __shfl(s_reg, 0);
        float ex_cur = __shfl(ex_reg, 0);
        unsigned int hv_cur = ((const unsigned int*)(hb + (size_t)s_cur * HID))[lane];
        for (int j = 0; j < deg; ++j) {
            const int more = (j + 1 < deg);
            const int jn = more ? j + 1 : j;
            const int s_nxt = __shfl(s_reg, jn);
            const float ex_nxt = __shfl(ex_reg, jn);
            unsigned int hv_nxt = more ? ((const unsigned int*)(hb + (size_t)s_nxt * HID))[lane] : 0u;
            a0 += ex_cur * bf_lo(hv_cur);
            a1 += ex_cur * bf_hi(hv_cur);
            s_cur = s_nxt; ex_cur = ex_nxt;
            if (more) hv_cur = hv_nxt;
        }
    } else {
        // rare fallback: classic 3-pass
        float m = -FLT_MAX;
        for (int i = start + lane; i < end; i += 64) {
            float e = al_src[csr_src[i]] + alD;
            e = (e > 0.f) ? e : NEG_SLOPE * e;
            m = fmaxf(m, e);
        }
#pragma unroll
        for (int off = 32; off; off >>= 1) m = fmaxf(m, __shfl_xor(m, off));
        float den = 0.f;
        for (int i = start + lane; i < end; i += 64) {
            float e = al_src[csr_src[i]] + alD;
            e = (e > 0.f) ? e : NEG_SLOPE * e;
            den += __expf(e - m);
        }
#pragma unroll
        for (int off = 32; off; off >>= 1) den += __shfl_xor(den, off);
        inv = 1.f / (den + 1e-16f);
        for (int i = start; i < end; ++i) {
            int s = csr_src[i];
            float e = al_src[s] + alD;
            e = (e > 0.f) ? e : NEG_SLOPE * e;
            float ex = __expf(e - m);
            unsigned int hv = ((const unsigned int*)(hb + (size_t)s * HID))[lane];
            a0 += ex * bf_lo(hv);
            a1 += ex * bf_hi(hv);
        }
    }

    float2 bv = *(const float2*)&bias[2 * lane];
    float o0 = a0 * inv + bv.x, o1 = a1 * inv + bv.y;
    if (RELU) { o0 = fmaxf(o0, 0.f); o1 = fmaxf(o1, 0.f); }
    *(float2*)&out[(size_t)n * HID + 2 * lane] = make_float2(o0, o1);
}

// ---------------- global mean pool (batch is sorted) -----------------------
__global__ void k_pool(const float* __restrict__ feat, const int* __restrict__ batch32,
                       float* __restrict__ out) {
    const int g = blockIdx.x;      // 256 graphs
    const int c = threadIdx.x;     // 128 features
    int lo = 0, hi = N_NODES;
    while (lo < hi) { int mid = (lo + hi) >> 1; if (batch32[mid] < g) lo = mid + 1; else hi = mid; }
    const int start = lo;
    hi = N_NODES;
    while (lo < hi) { int mid = (lo + hi) >> 1; if (batch32[mid] < g + 1) lo = mid + 1; else hi = mid; }
    const int end = lo;
    float acc = 0.f;
    for (int n = start; n < end; ++n) acc += feat[n * HID + c];
    int cnt = end - start;
    out[g * HID + c] = acc / (float)(cnt > 0 ? cnt : 1);
}

// ---------------------------------------------------------------------------
extern "C" void kernel_launch(void* const* d_in, const int* in_sizes, int n_in,
                              void* d_out, int out_size, void* d_ws, size_t ws_size,
                              hipStream_t stream) {
    const float* x   = (const float*)d_in[0];
    const void*  ei  = d_in[1];
    const void*  bat = d_in[2];
    const float* W1  = (const float*)d_in[3];
    const float* as1 = (const float*)d_in[4];
    const float* ad1 = (const float*)d_in[5];
    const float* b1  = (const float*)d_in[6];
    const float* W2  = (const float*)d_in[7];
    const float* as2 = (const float*)d_in[8];
    const float* ad2 = (const float*)d_in[9];
    const float* b2  = (const float*)d_in[10];
    const float* W3  = (const float*)d_in[11];
    const float* as3 = (const float*)d_in[12];
    const float* ad3 = (const float*)d_in[13];
    const float* b3  = (const float*)d_in[14];
    float* out = (float*)d_out;

    char* w = (char*)d_ws;
    auto carve = [&](size_t bytes) -> void* {
        void* p = (void*)w;
        w += (bytes + 255) & ~(size_t)255;
        return p;
    };
    int*   src32   = (int*)carve((size_t)N_EDGES * 4);
    int*   dst32   = (int*)carve((size_t)N_EDGES * 4);
    int*   batch32 = (int*)carve((size_t)N_NODES * 4);
    int*   deg     = (int*)carve((size_t)N_NODES * 4);   // becomes inclusive scan
    int*   offsets = (int*)carve((size_t)(N_NODES + 1) * 4);
    int*   bsum    = (int*)carve(4096);
    int*   cursor  = (int*)carve((size_t)N_NODES * 4);
    int*   csr_src = (int*)carve((size_t)E_TOT * 4);
    float* al_s    = (float*)carve((size_t)N_NODES * 4);
    float* al_d    = (float*)carve((size_t)N_NODES * 4);
    unsigned short* h = (unsigned short*)carve((size_t)N_NODES * HID * 2);   // bf16
    float* A       = (float*)carve((size_t)N_NODES * HID * 4);
    float* B       = (float*)carve((size_t)N_NODES * HID * 4);
    (void)ws_size; (void)in_sizes; (void)n_in; (void)out_size;

    hipMemsetAsync(deg,    0, (size_t)N_NODES * 4, stream);
    hipMemsetAsync(cursor, 0, (size_t)N_NODES * 4, stream);

    k_convert<<<(N_EDGES + 255) / 256, 256, 0, stream>>>(ei, bat, src32, dst32, batch32);
    k_hist<<<(E_TOT + 255) / 256, 256, 0, stream>>>(dst32, deg);

    const int NB_SCAN = (N_NODES + SCAN_B - 1) / SCAN_B;  // 98
    k_scan1<<<NB_SCAN, SCAN_B, 0, stream>>>(deg, bsum);
    k_scan2<<<1, 64, 0, stream>>>(bsum, NB_SCAN);
    k_scan3<<<NB_SCAN, SCAN_B, 0, stream>>>(deg, bsum, offsets);
    k_build<<<(E_TOT + 255) / 256, 256, 0, stream>>>(src32, dst32, offsets, cursor, csr_src);

    const int NODE_BLOCKS = (N_NODES + 3) / 4;           // aggr: 4 waves/block
    const int GEMM_BLOCKS = (N_NODES + BM - 1) / BM;     // 782

    // layer 1: x[50000,6] -> A
    k_gemm1<<<NODE_BLOCKS, 256, 0, stream>>>(x, W1, as1, ad1, h, al_s, al_d);
    k_gat_aggr<1><<<NODE_BLOCKS, 256, 0, stream>>>(offsets, csr_src, al_s, al_d, h, b1, A);

    // layer 2: A -> B
    k_gemm_tiled<<<GEMM_BLOCKS, 256, 0, stream>>>(A, W2, as2, ad2, h, al_s, al_d);
    k_gat_aggr<1><<<NODE_BLOCKS, 256, 0, stream>>>(offsets, csr_src, al_s, al_d, h, b2, B);

    // layer 3: B -> A (no relu)
    k_gemm_tiled<<<GEMM_BLOCKS, 256, 0, stream>>>(B, W3, as3, ad3, h, al_s, al_d);
    k_gat_aggr<0><<<NODE_BLOCKS, 256, 0, stream>>>(offsets, csr_src, al_s, al_d, h, b3, A);

    // global mean pool
    k_pool<<<NUM_GRAPHS, 128, 0, stream>>>(A, batch32, out);
}

// Round 16
// 424.102 us; speedup vs baseline: 1.4929x; 1.4929x over previous
//
#include <hip/hip_runtime.h>
#include <hip/hip_bf16.h>
#include <float.h>

#define N_NODES 50000
#define N_EDGES 600000
#define E_TOT   (N_EDGES + N_NODES)   /* 650000 incl. self loops */
#define NUM_GRAPHS 256
#define IN_CH 6
#define HID 128
#define NEG_SLOPE 0.2f
#define SCAN_B 512

// GEMM tile config
#define BM 64
#define BK 32

// ---------------- bf16 helpers (h table stored as raw bf16 bits) -----------
__device__ __forceinline__ unsigned short f2bf(float f) {
    unsigned int u = __float_as_uint(f);
    u += 0x7FFFu + ((u >> 16) & 1u);          // RNE
    return (unsigned short)(u >> 16);
}
__device__ __forceinline__ float bf_lo(unsigned int v) { return __uint_as_float(v << 16); }
__device__ __forceinline__ float bf_hi(unsigned int v) { return __uint_as_float(v & 0xFFFF0000u); }

// ---------------- int64-vs-int32 runtime detection -------------------------
__device__ __forceinline__ int detect_is64(const int* ei32) {
    int any = 0;
#pragma unroll
    for (int i = 1; i < 128; i += 2) any |= ei32[i];
    return any == 0;
}

__global__ void k_convert(const void* edge_index, const void* batch,
                          int* src32, int* dst32, int* batch32) {
    const int* ei32 = (const int*)edge_index;
    const int is64 = detect_is64(ei32);
    int i = blockIdx.x * blockDim.x + threadIdx.x;
    if (i < N_EDGES) {
        if (is64) {
            const long long* e = (const long long*)edge_index;
            src32[i] = (int)e[i];
            dst32[i] = (int)e[N_EDGES + i];
        } else {
            src32[i] = ei32[i];
            dst32[i] = ei32[N_EDGES + i];
        }
    }
    if (i < N_NODES) {
        batch32[i] = is64 ? (int)((const long long*)batch)[i]
                          : ((const int*)batch)[i];
    }
}

// ---------------- CSR build (counting sort by dst) -------------------------
__global__ void k_hist(const int* dst32, int* deg) {
    int e = blockIdx.x * blockDim.x + threadIdx.x;
    if (e >= E_TOT) return;
    int d = (e < N_EDGES) ? dst32[e] : (e - N_EDGES);
    atomicAdd(&deg[d], 1);
}

__global__ void k_scan1(int* deg, int* bsum) {
    __shared__ int tmp[SCAN_B];
    int i = blockIdx.x * SCAN_B + threadIdx.x;
    int v = (i < N_NODES) ? deg[i] : 0;
    tmp[threadIdx.x] = v;
    __syncthreads();
    for (int off = 1; off < SCAN_B; off <<= 1) {
        int t = (threadIdx.x >= off) ? tmp[threadIdx.x - off] : 0;
        __syncthreads();
        tmp[threadIdx.x] += t;
        __syncthreads();
    }
    if (i < N_NODES) deg[i] = tmp[threadIdx.x];
    if (threadIdx.x == SCAN_B - 1) bsum[blockIdx.x] = tmp[threadIdx.x];
}

__global__ void k_scan2(int* bsum, int nb) {
    if (blockIdx.x == 0 && threadIdx.x == 0) {
        int run = 0;
        for (int b = 0; b < nb; ++b) { int t = bsum[b]; bsum[b] = run; run += t; }
    }
}

__global__ void k_scan3(const int* incl, const int* bsum, int* offsets) {
    int i = blockIdx.x * SCAN_B + threadIdx.x;
    if (i < N_NODES) offsets[i + 1] = incl[i] + bsum[blockIdx.x];
    if (i == 0) offsets[0] = 0;
}

__global__ void k_build(const int* src32, const int* dst32, const int* offsets,
                        int* cursor, int* csr_src) {
    int e = blockIdx.x * blockDim.x + threadIdx.x;
    if (e >= E_TOT) return;
    int s, d;
    if (e < N_EDGES) { s = src32[e]; d = dst32[e]; }
    else             { s = d = e - N_EDGES; }
    int pos = offsets[d] + atomicAdd(&cursor[d], 1);
    csr_src[pos] = s;
}

// ---------------- layer-1 GEMM (K=6, trivial) ------------------------------
__global__ void k_gemm1(const float* __restrict__ x, const float* __restrict__ W,
                        const float* __restrict__ asrc, const float* __restrict__ adst,
                        unsigned short* __restrict__ h, float* al_src, float* al_dst) {
    int wave = (blockIdx.x * blockDim.x + threadIdx.x) >> 6;
    int lane = threadIdx.x & 63;
    if (wave >= N_NODES) return;
    const int n = wave;
    float h0 = 0.f, h1 = 0.f;
#pragma unroll
    for (int k = 0; k < IN_CH; ++k) {
        float xk = x[n * IN_CH + k];
        float2 w = *(const float2*)&W[k * HID + 2 * lane];
        h0 += xk * w.x; h1 += xk * w.y;
    }
    unsigned int hp = (unsigned int)f2bf(h0) | ((unsigned int)f2bf(h1) << 16);
    ((unsigned int*)h)[(size_t)n * 64 + lane] = hp;
    float2 as = *(const float2*)&asrc[2 * lane];
    float2 ad = *(const float2*)&adst[2 * lane];
    float ps = h0 * as.x + h1 * as.y;
    float pd = h0 * ad.x + h1 * ad.y;
#pragma unroll
    for (int off = 32; off; off >>= 1) {
        ps += __shfl_xor(ps, off);
        pd += __shfl_xor(pd, off);
    }
    if (lane == 0) { al_src[n] = ps; al_dst[n] = pd; }
}

// ---------------- layers 2/3 GEMM: LDS-tiled [N,128]x[128,128] -------------
__global__ __launch_bounds__(256) void k_gemm_tiled(
    const float* __restrict__ X, const float* __restrict__ W,
    const float* __restrict__ asrc, const float* __restrict__ adst,
    unsigned short* __restrict__ h, float* __restrict__ al_src, float* __restrict__ al_dst)
{
    __shared__ float As[BK][BM + 4];
    __shared__ float Bs[BK][HID];

    const int tid = threadIdx.x;
    const int node_base = blockIdx.x * BM;
    const int tn = tid & 31;
    const int tm = tid >> 5;

    float acc[8][4];
#pragma unroll
    for (int i = 0; i < 8; ++i)
#pragma unroll
        for (int j = 0; j < 4; ++j) acc[i][j] = 0.f;

    const int sa_node  = tid & 63;
    const int sa_kpart = tid >> 6;
    int gnode = node_base + sa_node;
    if (gnode >= N_NODES) gnode = N_NODES - 1;

    const int sb_k = tid >> 3;
    const int sb_c = (tid & 7) * 16;

    for (int k0 = 0; k0 < HID; k0 += BK) {
        const float4 xa = *(const float4*)&X[(size_t)gnode * HID + k0 + sa_kpart * 8];
        const float4 xb = *(const float4*)&X[(size_t)gnode * HID + k0 + sa_kpart * 8 + 4];
        {
            const int kb = sa_kpart * 8;
            As[kb + 0][sa_node] = xa.x; As[kb + 1][sa_node] = xa.y;
            As[kb + 2][sa_node] = xa.z; As[kb + 3][sa_node] = xa.w;
            As[kb + 4][sa_node] = xb.x; As[kb + 5][sa_node] = xb.y;
            As[kb + 6][sa_node] = xb.z; As[kb + 7][sa_node] = xb.w;
        }
        {
            const float* wsrc = &W[(size_t)(k0 + sb_k) * HID + sb_c];
            float4 w0 = *(const float4*)(wsrc + 0);
            float4 w1 = *(const float4*)(wsrc + 4);
            float4 w2 = *(const float4*)(wsrc + 8);
            float4 w3 = *(const float4*)(wsrc + 12);
            *(float4*)&Bs[sb_k][sb_c + 0]  = w0;
            *(float4*)&Bs[sb_k][sb_c + 4]  = w1;
            *(float4*)&Bs[sb_k][sb_c + 8]  = w2;
            *(float4*)&Bs[sb_k][sb_c + 12] = w3;
        }
        __syncthreads();

#pragma unroll
        for (int kk = 0; kk < BK; ++kk) {
            const float4 b  = *(const float4*)&Bs[kk][tn * 4];
            const float4 a0 = *(const float4*)&As[kk][tm * 8];
            const float4 a1 = *(const float4*)&As[kk][tm * 8 + 4];
            acc[0][0] += a0.x * b.x; acc[0][1] += a0.x * b.y; acc[0][2] += a0.x * b.z; acc[0][3] += a0.x * b.w;
            acc[1][0] += a0.y * b.x; acc[1][1] += a0.y * b.y; acc[1][2] += a0.y * b.z; acc[1][3] += a0.y * b.w;
            acc[2][0] += a0.z * b.x; acc[2][1] += a0.z * b.y; acc[2][2] += a0.z * b.z; acc[2][3] += a0.z * b.w;
            acc[3][0] += a0.w * b.x; acc[3][1] += a0.w * b.y; acc[3][2] += a0.w * b.z; acc[3][3] += a0.w * b.w;
            acc[4][0] += a1.x * b.x; acc[4][1] += a1.x * b.y; acc[4][2] += a1.x * b.z; acc[4][3] += a1.x * b.w;
            acc[5][0] += a1.y * b.x; acc[5][1] += a1.y * b.y; acc[5][2] += a1.y * b.z; acc[5][3] += a1.y * b.w;
            acc[6][0] += a1.z * b.x; acc[6][1] += a1.z * b.y; acc[6][2] += a1.z * b.z; acc[6][3] += a1.z * b.w;
            acc[7][0] += a1.w * b.x; acc[7][1] += a1.w * b.y; acc[7][2] += a1.w * b.z; acc[7][3] += a1.w * b.w;
        }
        __syncthreads();
    }

    const float4 as4 = *(const float4*)&asrc[tn * 4];
    const float4 ad4 = *(const float4*)&adst[tn * 4];
#pragma unroll
    for (int i = 0; i < 8; ++i) {
        const int node = node_base + tm * 8 + i;
        float ps = acc[i][0] * as4.x + acc[i][1] * as4.y + acc[i][2] * as4.z + acc[i][3] * as4.w;
        float pd = acc[i][0] * ad4.x + acc[i][1] * ad4.y + acc[i][2] * ad4.z + acc[i][3] * ad4.w;
#pragma unroll
        for (int off = 16; off; off >>= 1) {
            ps += __shfl_xor(ps, off);
            pd += __shfl_xor(pd, off);
        }
        if (node < N_NODES) {
            unsigned int u0 = (unsigned int)f2bf(acc[i][0]) | ((unsigned int)f2bf(acc[i][1]) << 16);
            unsigned int u1 = (unsigned int)f2bf(acc[i][2]) | ((unsigned int)f2bf(acc[i][3]) << 16);
            *(uint2*)(h + (size_t)node * HID + tn * 4) = make_uint2(u0, u1);
            if (tn == 0) { al_src[node] = ps; al_dst[node] = pd; }
        }
    }
}

// ---------------- GAT aggregation (gather, register-cached softmax) --------
template <int RELU>
__global__ void k_gat_aggr(const int* __restrict__ offsets, const int* __restrict__ csr_src,
                           const float* __restrict__ al_src, const float* __restrict__ al_dst,
                           const unsigned short* __restrict__ hb, const float* __restrict__ bias,
                           float* __restrict__ out) {
    int wave = (blockIdx.x * blockDim.x + threadIdx.x) >> 6;
    int lane = threadIdx.x & 63;
    if (wave >= N_NODES) return;
    const int n = wave;
    const int start = offsets[n], end = offsets[n + 1];
    const int deg = end - start;
    const float alD = al_dst[n];

    float a0 = 0.f, a1 = 0.f;
    float inv;

    if (deg <= 64) {
        // one strided gather: cache src index + exp weight per lane
        const int idx = start + (lane < deg ? lane : 0);
        const int s_reg = csr_src[idx];
        float e = al_src[s_reg] + alD;
        e = (e > 0.f) ? e : NEG_SLOPE * e;
        float ev = (lane < deg) ? e : -FLT_MAX;
#pragma unroll
        for (int off = 32; off; off >>= 1) ev = fmaxf(ev, __shfl_xor(ev, off));
        const float ex_reg = (lane < deg) ? __expf(e - ev) : 0.f;
        float den = ex_reg;
#pragma unroll
        for (int off = 32; off; off >>= 1) den += __shfl_xor(den, off);
        inv = 1.f / (den + 1e-16f);

        // weighted row gather, 1-deep pipeline; s/ex broadcast from registers
        int s_cur = __shfl(s_reg, 0);
        float ex_cur = __shfl(ex_reg, 0);
        unsigned int hv_cur = ((const unsigned int*)(hb + (size_t)s_cur * HID))[lane];
        for (int j = 0; j < deg; ++j) {
            const int more = (j + 1 < deg);
            const int jn = more ? j + 1 : j;
            const int s_nxt = __shfl(s_reg, jn);
            const float ex_nxt = __shfl(ex_reg, jn);
            unsigned int hv_nxt = more ? ((const unsigned int*)(hb + (size_t)s_nxt * HID))[lane] : 0u;
            a0 += ex_cur * bf_lo(hv_cur);
            a1 += ex_cur * bf_hi(hv_cur);
            s_cur = s_nxt; ex_cur = ex_nxt;
            if (more) hv_cur = hv_nxt;
        }
    } else {
        // rare fallback: classic 3-pass
        float m = -FLT_MAX;
        for (int i = start + lane; i < end; i += 64) {
            float e = al_src[csr_src[i]] + alD;
            e = (e > 0.f) ? e : NEG_SLOPE * e;
            m = fmaxf(m, e);
        }
#pragma unroll
        for (int off = 32; off; off >>= 1) m = fmaxf(m, __shfl_xor(m, off));
        float den = 0.f;
        for (int i = start + lane; i < end; i += 64) {
            float e = al_src[csr_src[i]] + alD;
            e = (e > 0.f) ? e : NEG_SLOPE * e;
            den += __expf(e - m);
        }
#pragma unroll
        for (int off = 32; off; off >>= 1) den += __shfl_xor(den, off);
        inv = 1.f / (den + 1e-16f);
        for (int i = start; i < end; ++i) {
            int s = csr_src[i];
            float e = al_src[s] + alD;
            e = (e > 0.f) ? e : NEG_SLOPE * e;
            float ex = __expf(e - m);
            unsigned int hv = ((const unsigned int*)(hb + (size_t)s * HID))[lane];
            a0 += ex * bf_lo(hv);
            a1 += ex * bf_hi(hv);
        }
    }

    float2 bv = *(const float2*)&bias[2 * lane];
    float o0 = a0 * inv + bv.x, o1 = a1 * inv + bv.y;
    if (RELU) { o0 = fmaxf(o0, 0.f); o1 = fmaxf(o1, 0.f); }
    *(float2*)&out[(size_t)n * HID + 2 * lane] = make_float2(o0, o1);
}

// ---------------- global mean pool (batch sorted; 16 rows in flight) -------
__global__ __launch_bounds__(512) void k_pool(const float* __restrict__ feat,
                                              const int* __restrict__ batch32,
                                              float* __restrict__ out) {
    __shared__ float4 red[16][32];
    const int g  = blockIdx.x;          // 256 graphs
    const int c  = threadIdx.x & 31;    // channel quad index (c*4)
    const int rg = threadIdx.x >> 5;    // row group 0..15

    int lo = 0, hi = N_NODES;
    while (lo < hi) { int mid = (lo + hi) >> 1; if (batch32[mid] < g) lo = mid + 1; else hi = mid; }
    const int start = lo;
    hi = N_NODES;
    while (lo < hi) { int mid = (lo + hi) >> 1; if (batch32[mid] < g + 1) lo = mid + 1; else hi = mid; }
    const int end = lo;

    float4 acc = make_float4(0.f, 0.f, 0.f, 0.f);
    for (int n = start + rg; n < end; n += 16) {
        float4 v = *(const float4*)&feat[(size_t)n * HID + c * 4];
        acc.x += v.x; acc.y += v.y; acc.z += v.z; acc.w += v.w;
    }
    red[rg][c] = acc;
    __syncthreads();
#pragma unroll
    for (int s = 8; s; s >>= 1) {
        if (rg < s) {
            float4 o = red[rg + s][c];
            float4 m = red[rg][c];
            m.x += o.x; m.y += o.y; m.z += o.z; m.w += o.w;
            red[rg][c] = m;
        }
        __syncthreads();
    }
    if (rg == 0) {
        const int cnt = end - start;
        const float invc = 1.f / (float)(cnt > 0 ? cnt : 1);
        float4 m = red[0][c];
        m.x *= invc; m.y *= invc; m.z *= invc; m.w *= invc;
        *(float4*)&out[(size_t)g * HID + c * 4] = m;
    }
}

// ---------------------------------------------------------------------------
extern "C" void kernel_launch(void* const* d_in, const int* in_sizes, int n_in,
                              void* d_out, int out_size, void* d_ws, size_t ws_size,
                              hipStream_t stream) {
    const float* x   = (const float*)d_in[0];
    const void*  ei  = d_in[1];
    const void*  bat = d_in[2];
    const float* W1  = (const float*)d_in[3];
    const float* as1 = (const float*)d_in[4];
    const float* ad1 = (const float*)d_in[5];
    const float* b1  = (const float*)d_in[6];
    const float* W2  = (const float*)d_in[7];
    const float* as2 = (const float*)d_in[8];
    const float* ad2 = (const float*)d_in[9];
    const float* b2  = (const float*)d_in[10];
    const float* W3  = (const float*)d_in[11];
    const float* as3 = (const float*)d_in[12];
    const float* ad3 = (const float*)d_in[13];
    const float* b3  = (const float*)d_in[14];
    float* out = (float*)d_out;

    char* w = (char*)d_ws;
    auto carve = [&](size_t bytes) -> void* {
        void* p = (void*)w;
        w += (bytes + 255) & ~(size_t)255;
        return p;
    };
    int*   src32   = (int*)carve((size_t)N_EDGES * 4);
    int*   dst32   = (int*)carve((size_t)N_EDGES * 4);
    int*   batch32 = (int*)carve((size_t)N_NODES * 4);
    int*   deg     = (int*)carve((size_t)N_NODES * 4);   // becomes inclusive scan
    int*   offsets = (int*)carve((size_t)(N_NODES + 1) * 4);
    int*   bsum    = (int*)carve(4096);
    int*   cursor  = (int*)carve((size_t)N_NODES * 4);
    int*   csr_src = (int*)carve((size_t)E_TOT * 4);
    float* al_s    = (float*)carve((size_t)N_NODES * 4);
    float* al_d    = (float*)carve((size_t)N_NODES * 4);
    unsigned short* h = (unsigned short*)carve((size_t)N_NODES * HID * 2);   // bf16
    float* A       = (float*)carve((size_t)N_NODES * HID * 4);
    float* B       = (float*)carve((size_t)N_NODES * HID * 4);
    (void)ws_size; (void)in_sizes; (void)n_in; (void)out_size;

    hipMemsetAsync(deg,    0, (size_t)N_NODES * 4, stream);
    hipMemsetAsync(cursor, 0, (size_t)N_NODES * 4, stream);

    k_convert<<<(N_EDGES + 255) / 256, 256, 0, stream>>>(ei, bat, src32, dst32, batch32);
    k_hist<<<(E_TOT + 255) / 256, 256, 0, stream>>>(dst32, deg);

    const int NB_SCAN = (N_NODES + SCAN_B - 1) / SCAN_B;  // 98
    k_scan1<<<NB_SCAN, SCAN_B, 0, stream>>>(deg, bsum);
    k_scan2<<<1, 64, 0, stream>>>(bsum, NB_SCAN);
    k_scan3<<<NB_SCAN, SCAN_B, 0, stream>>>(deg, bsum, offsets);
    k_build<<<(E_TOT + 255) / 256, 256, 0, stream>>>(src32, dst32, offsets, cursor, csr_src);

    const int NODE_BLOCKS = (N_NODES + 3) / 4;           // aggr: 4 waves/block
    const int GEMM_BLOCKS = (N_NODES + BM - 1) / BM;     // 782

    // layer 1: x[50000,6] -> A
    k_gemm1<<<NODE_BLOCKS, 256, 0, stream>>>(x, W1, as1, ad1, h, al_s, al_d);
    k_gat_aggr<1><<<NODE_BLOCKS, 256, 0, stream>>>(offsets, csr_src, al_s, al_d, h, b1, A);

    // layer 2: A -> B
    k_gemm_tiled<<<GEMM_BLOCKS, 256, 0, stream>>>(A, W2, as2, ad2, h, al_s, al_d);
    k_gat_aggr<1><<<NODE_BLOCKS, 256, 0, stream>>>(offsets, csr_src, al_s, al_d, h, b2, B);

    // layer 3: B -> A (no relu)
    k_gemm_tiled<<<GEMM_BLOCKS, 256, 0, stream>>>(B, W3, as3, ad3, h, al_s, al_d);
    k_gat_aggr<0><<<NODE_BLOCKS, 256, 0, stream>>>(offsets, csr_src, al_s, al_d, h, b3, A);

    // global mean pool
    k_pool<<<NUM_GRAPHS, 512, 0, stream>>>(A, batch32, out);
}